// Round 1
// baseline (657.518 us; speedup 1.0000x reference)
//
#include <hip/hip_runtime.h>

// ---------------------------------------------------------------------------
// WindowAttention: x[2048,49,512] fp32 -> out[2048,49,512] fp32
//   qkv = x @ Wqkv^T + b ; per-(b,h) 49x49 attention with window mask ; proj.
// Strategy: bf16 MFMA (16x16x32) for both GEMMs + fused per-(b,h) attention.
// ---------------------------------------------------------------------------

typedef unsigned short ushort_t;
typedef __bf16 bf16x8 __attribute__((ext_vector_type(8)));
typedef float f32x4 __attribute__((ext_vector_type(4)));
typedef unsigned short us8 __attribute__((ext_vector_type(8)));

#define SCALE_F 0.17677669529663687f   // 32^-0.5
constexpr size_t QKV_REG = 2048ULL * 16 * 49 * 32;   // 51,380,224 elems per q/k/v region

// RNE float -> bf16 (as raw ushort)
__device__ __forceinline__ ushort_t f2bf(float f) {
  unsigned u = __builtin_bit_cast(unsigned, f);
  u += 0x7FFFu + ((u >> 16) & 1u);
  return (ushort_t)(u >> 16);
}

// async global->LDS, 16B per lane; lds base must be wave-uniform
__device__ __forceinline__ void gload_lds16(const void* g, void* l) {
  __builtin_amdgcn_global_load_lds(
      (const __attribute__((address_space(1))) void*)g,
      (__attribute__((address_space(3))) void*)l, 16, 0, 0);
}

// ---------------------------------------------------------------------------
// fp32 -> bf16 conversion, 4 elems/thread
// ---------------------------------------------------------------------------
__global__ __launch_bounds__(256) void k_cvt(const float* __restrict__ in,
                                             ushort_t* __restrict__ out, int n4) {
  int i = blockIdx.x * blockDim.x + threadIdx.x;
  if (i >= n4) return;
  float4 v = reinterpret_cast<const float4*>(in)[i];
  ushort4 o = make_ushort4(f2bf(v.x), f2bf(v.y), f2bf(v.z), f2bf(v.w));
  reinterpret_cast<ushort4*>(out)[i] = o;
}

// ---------------------------------------------------------------------------
// GEMM: C[m][o] = sum_k A[m][k] * W[o][k] + bias[o]
// A: [M,512] bf16 row-major, W: [O,512] bf16 row-major. Tile 128x128, BK=64,
// 4 waves (each 64x64 = 4x4 fragments of 16x16x32), global_load_lds staging.
// EPI=0: scatter to qkv layout [3][B,H,N,d] bf16.  EPI=1: fp32 out.
// ---------------------------------------------------------------------------
template <int EPI>
__global__ __launch_bounds__(256) void k_gemm(const ushort_t* __restrict__ A,
                                              const ushort_t* __restrict__ W,
                                              const float* __restrict__ bias,
                                              ushort_t* __restrict__ out_qkv,
                                              float* __restrict__ out_f,
                                              int nt_o) {
  __shared__ __align__(16) ushort_t As[128][64];
  __shared__ __align__(16) ushort_t Ws[128][64];

  const int tid  = threadIdx.x;
  const int lane = tid & 63;
  const int wv   = tid >> 6;          // wave id 0..3
  const int wr   = wv >> 1, wc = wv & 1;
  const int bm   = blockIdx.x / nt_o;
  const int bo   = blockIdx.x - bm * nt_o;
  const size_t m0 = (size_t)bm * 128;
  const int o0    = bo * 128;

  f32x4 acc[4][4];
#pragma unroll
  for (int i = 0; i < 4; i++)
#pragma unroll
    for (int j = 0; j < 4; j++) acc[i][j] = f32x4{0.f, 0.f, 0.f, 0.f};

  const int srow   = wv * 32 + (lane >> 3);   // staging row (per lane)
  const int schunk = (lane & 7) * 8;          // staging col (elems)

  for (int kt = 0; kt < 8; ++kt) {
    const int k0 = kt * 64;
#pragma unroll
    for (int i = 0; i < 4; i++) {
      const ushort_t* g = A + (m0 + srow + i * 8) * 512 + k0 + schunk;
      gload_lds16(g, &As[wv * 32 + i * 8][0]);
    }
#pragma unroll
    for (int i = 0; i < 4; i++) {
      const ushort_t* g = W + (size_t)(o0 + srow + i * 8) * 512 + k0 + schunk;
      gload_lds16(g, &Ws[wv * 32 + i * 8][0]);
    }
    __syncthreads();
#pragma unroll
    for (int kk = 0; kk < 2; ++kk) {
      const int kc = kk * 32 + (lane >> 4) * 8;
      uint4 ar[4], br[4];
#pragma unroll
      for (int mi = 0; mi < 4; mi++)
        ar[mi] = *reinterpret_cast<const uint4*>(&As[wr * 64 + mi * 16 + (lane & 15)][kc]);
#pragma unroll
      for (int ni = 0; ni < 4; ni++)
        br[ni] = *reinterpret_cast<const uint4*>(&Ws[wc * 64 + ni * 16 + (lane & 15)][kc]);
#pragma unroll
      for (int mi = 0; mi < 4; mi++)
#pragma unroll
        for (int ni = 0; ni < 4; ni++)
          acc[mi][ni] = __builtin_amdgcn_mfma_f32_16x16x32_bf16(
              __builtin_bit_cast(bf16x8, ar[mi]),
              __builtin_bit_cast(bf16x8, br[ni]), acc[mi][ni], 0, 0, 0);
    }
    __syncthreads();
  }

  const int colbase = lane & 15;
  const int rowgrp  = (lane >> 4) * 4;

  if constexpr (EPI == 1) {
#pragma unroll
    for (int ni = 0; ni < 4; ni++) {
      const int o = o0 + wc * 64 + ni * 16 + colbase;
      const float bv = bias[o];
#pragma unroll
      for (int mi = 0; mi < 4; mi++) {
        const size_t mrow = m0 + wr * 64 + mi * 16 + rowgrp;
#pragma unroll
        for (int r = 0; r < 4; r++)
          out_f[(mrow + r) * 512 + o] = acc[mi][ni][r] + bv;
      }
    }
  } else {
#pragma unroll
    for (int mi = 0; mi < 4; mi++) {
#pragma unroll
      for (int r = 0; r < 4; r++) {
        const int t = (int)m0 + wr * 64 + mi * 16 + rowgrp + r;  // token
        const int b = t / 49;
        const int n = t - b * 49;
#pragma unroll
        for (int ni = 0; ni < 4; ni++) {
          const int o = o0 + wc * 64 + ni * 16 + colbase;
          const int which = o >> 9;
          const int h = (o >> 5) & 15;
          const int dd = o & 31;
          const size_t dst = (size_t)which * QKV_REG +
                             (((size_t)b * 16 + h) * 49 + n) * 32 + dd;
          out_qkv[dst] = f2bf(acc[mi][ni][r] + bias[o]);
        }
      }
    }
  }
}

// ---------------------------------------------------------------------------
// Attention: one block per (b,h). 4 waves, wave mt owns query rows
// [16*mt, 16*mt+16). S = scale*Q K^T + mask ; softmax ; O = P V / rowsum.
// ---------------------------------------------------------------------------
__global__ __launch_bounds__(256) void k_attn(const ushort_t* __restrict__ qkv,
                                              const float* __restrict__ mask,
                                              ushort_t* __restrict__ aout) {
  __shared__ __align__(16) ushort_t Vt[32][64];      // V transposed: Vt[d][n]
  __shared__ __align__(16) ushort_t Ps[4][16][64];   // per-wave P tile

  const int tid  = threadIdx.x;
  const int lane = tid & 63;
  const int mt   = tid >> 6;              // wave id = query m-tile
  const int bh   = blockIdx.x;
  const int b    = bh >> 4, h = bh & 15;
  const int w    = b & 63;                // window index
  const size_t base = (size_t)bh * (49 * 32);
  const ushort_t* qb = qkv + base;
  const ushort_t* kb = qkv + QKV_REG + base;
  const ushort_t* vb = qkv + 2 * QKV_REG + base;

  // zero Vt (covers padded keys 49..63), then load V transposed
  reinterpret_cast<uint4*>(&Vt[0][0])[tid] = make_uint4(0, 0, 0, 0);
  __syncthreads();
  if (tid < 196) {
    const int n = tid >> 2, d0 = (tid & 3) * 8;
    uint4 raw = *reinterpret_cast<const uint4*>(vb + n * 32 + d0);
    us8 e = __builtin_bit_cast(us8, raw);
#pragma unroll
    for (int j = 0; j < 8; j++) Vt[d0 + j][n] = e[j];
  }
  __syncthreads();

  const int arow = lane & 15;
  const int kc   = (lane >> 4) * 8;

  // S = Q K^T (one K=32 MFMA per 16x16 tile). Q/K fragments direct from global.
  uint4 qraw = *reinterpret_cast<const uint4*>(qb + (mt * 16 + arow) * 32 + kc);
  bf16x8 qa = __builtin_bit_cast(bf16x8, qraw);
  f32x4 s[4];
#pragma unroll
  for (int ni = 0; ni < 4; ni++) {
    uint4 kraw = *reinterpret_cast<const uint4*>(kb + (ni * 16 + arow) * 32 + kc);
    f32x4 z = {0.f, 0.f, 0.f, 0.f};
    s[ni] = __builtin_amdgcn_mfma_f32_16x16x32_bf16(
        qa, __builtin_bit_cast(bf16x8, kraw), z, 0, 0, 0);
  }

  // softmax: row r of D lives in 16-lane group, col = lane&15 (+16*ni)
  const int rg = (lane >> 4) * 4;
  float rsum[4];
#pragma unroll
  for (int r = 0; r < 4; r++) {
    const int qr = mt * 16 + rg + r;
    float sv[4];
    float mx = -1e30f;
#pragma unroll
    for (int ni = 0; ni < 4; ni++) {
      const int col = ni * 16 + arow;
      float v;
      if (qr < 49 && col < 49)
        v = s[ni][r] * SCALE_F + mask[(size_t)w * 2401 + qr * 49 + col];
      else
        v = -1e30f;
      sv[ni] = v;
      mx = fmaxf(mx, v);
    }
#pragma unroll
    for (int off = 1; off < 16; off <<= 1) mx = fmaxf(mx, __shfl_xor(mx, off));
    float sum = 0.f;
#pragma unroll
    for (int ni = 0; ni < 4; ni++) {
      float p = __expf(sv[ni] - mx);
      sum += p;
      Ps[mt][rg + r][ni * 16 + arow] = f2bf(p);
    }
#pragma unroll
    for (int off = 1; off < 16; off <<= 1) sum += __shfl_xor(sum, off);
    rsum[r] = sum;
  }

  __syncthreads();  // order Ps ushort writes vs uint4 reads (cross-type aliasing)

  // O = P V : P rows from Ps (A-frag), V columns from Vt (B-frag)
  f32x4 o0 = {0.f, 0.f, 0.f, 0.f}, o1 = {0.f, 0.f, 0.f, 0.f};
#pragma unroll
  for (int kk = 0; kk < 2; kk++) {
    uint4 praw = *reinterpret_cast<const uint4*>(&Ps[mt][arow][kk * 32 + kc]);
    bf16x8 pa = __builtin_bit_cast(bf16x8, praw);
    uint4 v0 = *reinterpret_cast<const uint4*>(&Vt[arow][kk * 32 + kc]);
    uint4 v1 = *reinterpret_cast<const uint4*>(&Vt[16 + arow][kk * 32 + kc]);
    o0 = __builtin_amdgcn_mfma_f32_16x16x32_bf16(pa, __builtin_bit_cast(bf16x8, v0), o0, 0, 0, 0);
    o1 = __builtin_amdgcn_mfma_f32_16x16x32_bf16(pa, __builtin_bit_cast(bf16x8, v1), o1, 0, 0, 0);
  }

  // store: aout[(b*49+qr)*512 + h*32 + d] bf16
#pragma unroll
  for (int r = 0; r < 4; r++) {
    const int qr = mt * 16 + rg + r;
    if (qr < 49) {
      const float inv = 1.f / rsum[r];
      aout[((size_t)b * 49 + qr) * 512 + h * 32 + arow]      = f2bf(o0[r] * inv);
      aout[((size_t)b * 49 + qr) * 512 + h * 32 + 16 + arow] = f2bf(o1[r] * inv);
    }
  }
}

// ---------------------------------------------------------------------------
// launch
// ---------------------------------------------------------------------------
extern "C" void kernel_launch(void* const* d_in, const int* in_sizes, int n_in,
                              void* d_out, int out_size, void* d_ws, size_t ws_size,
                              hipStream_t stream) {
  const float* x      = (const float*)d_in[0];
  const float* mask   = (const float*)d_in[1];
  const float* W_qkv  = (const float*)d_in[2];
  const float* b_qkv  = (const float*)d_in[3];
  const float* W_proj = (const float*)d_in[4];
  const float* b_proj = (const float*)d_in[5];
  float* out = (float*)d_out;

  // ws layout (bf16 elems): xb | qkv(q,k,v) | attn_out | Wqkv_b | Wproj_b
  ushort_t* ws     = (ushort_t*)d_ws;
  ushort_t* xb     = ws;                                  // 51,380,224
  ushort_t* qkvb   = ws + 51380224UL;                     // 3*51,380,224
  ushort_t* aoutb  = ws + 205520896UL;                    // 51,380,224
  ushort_t* wqkvb  = ws + 256901120UL;                    // 786,432
  ushort_t* wprojb = ws + 257687552UL;                    // 262,144

  const int n4x = 51380224 / 4, n4q = 786432 / 4, n4p = 262144 / 4;
  k_cvt<<<(n4x + 255) / 256, 256, 0, stream>>>(x, xb, n4x);
  k_cvt<<<(n4q + 255) / 256, 256, 0, stream>>>(W_qkv, wqkvb, n4q);
  k_cvt<<<(n4p + 255) / 256, 256, 0, stream>>>(W_proj, wprojb, n4p);

  // GEMM1: [100352,512] x [1536,512]^T -> qkv scatter. 784 x 12 tiles.
  k_gemm<0><<<784 * 12, 256, 0, stream>>>(xb, wqkvb, b_qkv, qkvb, nullptr, 12);

  // attention: one block per (b,h)
  k_attn<<<2048 * 16, 256, 0, stream>>>(qkvb, mask, aoutb);

  // GEMM2: [100352,512] x [512,512]^T + bias -> fp32 out. 784 x 4 tiles.
  k_gemm<1><<<784 * 4, 256, 0, stream>>>(aoutb, wprojb, b_proj, nullptr, out, 4);
}

// Round 2
// 592.918 us; speedup vs baseline: 1.1090x; 1.1090x over previous
//
#include <hip/hip_runtime.h>

// ---------------------------------------------------------------------------
// WindowAttention: x[2048,49,512] fp32 -> out[2048,49,512] fp32
//   qkv = x @ Wqkv^T + b ; per-(b,h) 49x49 attention with window mask ; proj.
// Strategy: bf16 MFMA (16x16x32) for both GEMMs + fused per-(b,h) attention.
// R1: LDS XOR-swizzle (T2) on GEMM tiles + attn Vt/Ps (16-way -> 2-way bank
//     conflict); bijective XCD swizzle (T1) on both GEMM grids.
// ---------------------------------------------------------------------------

typedef unsigned short ushort_t;
typedef __bf16 bf16x8 __attribute__((ext_vector_type(8)));
typedef float f32x4 __attribute__((ext_vector_type(4)));
typedef unsigned short us8 __attribute__((ext_vector_type(8)));

#define SCALE_F 0.17677669529663687f   // 32^-0.5
constexpr size_t QKV_REG = 2048ULL * 16 * 49 * 32;   // 51,380,224 elems per q/k/v region

// RNE float -> bf16 (as raw ushort)
__device__ __forceinline__ ushort_t f2bf(float f) {
  unsigned u = __builtin_bit_cast(unsigned, f);
  u += 0x7FFFu + ((u >> 16) & 1u);
  return (ushort_t)(u >> 16);
}

// async global->LDS, 16B per lane; lds base must be wave-uniform
__device__ __forceinline__ void gload_lds16(const void* g, void* l) {
  __builtin_amdgcn_global_load_lds(
      (const __attribute__((address_space(1))) void*)g,
      (__attribute__((address_space(3))) void*)l, 16, 0, 0);
}

// ---------------------------------------------------------------------------
// fp32 -> bf16 conversion, 4 elems/thread
// ---------------------------------------------------------------------------
__global__ __launch_bounds__(256) void k_cvt(const float* __restrict__ in,
                                             ushort_t* __restrict__ out, int n4) {
  int i = blockIdx.x * blockDim.x + threadIdx.x;
  if (i >= n4) return;
  float4 v = reinterpret_cast<const float4*>(in)[i];
  ushort4 o = make_ushort4(f2bf(v.x), f2bf(v.y), f2bf(v.z), f2bf(v.w));
  reinterpret_cast<ushort4*>(out)[i] = o;
}

// ---------------------------------------------------------------------------
// GEMM: C[m][o] = sum_k A[m][k] * W[o][k] + bias[o]
// A: [M,512] bf16 row-major, W: [O,512] bf16 row-major. Tile 128x128, BK=64,
// 4 waves (each 64x64 = 4x4 fragments of 16x16x32), global_load_lds staging.
// LDS rows are 8 chunks of 16B; chunk index XOR-swizzled with (row&7):
//   slot (row, c) holds logical chunk c ^ (row&7).
// Staged via pre-swizzled GLOBAL source (gload_lds dest is linear).
// EPI=0: scatter to qkv layout [3][B,H,N,d] bf16.  EPI=1: fp32 out.
// ---------------------------------------------------------------------------
template <int EPI>
__global__ __launch_bounds__(256) void k_gemm(const ushort_t* __restrict__ A,
                                              const ushort_t* __restrict__ W,
                                              const float* __restrict__ bias,
                                              ushort_t* __restrict__ out_qkv,
                                              float* __restrict__ out_f,
                                              int nt_o) {
  __shared__ __align__(16) ushort_t As[128][64];
  __shared__ __align__(16) ushort_t Ws[128][64];

  const int tid  = threadIdx.x;
  const int lane = tid & 63;
  const int wv   = tid >> 6;          // wave id 0..3
  const int wr   = wv >> 1, wc = wv & 1;

  // bijective XCD swizzle: gridDim.x % 8 == 0 guaranteed by launch
  const int cpx = gridDim.x >> 3;
  const int lid = (blockIdx.x & 7) * cpx + (blockIdx.x >> 3);
  const int bm  = lid / nt_o;
  const int bo  = lid - bm * nt_o;
  const size_t m0 = (size_t)bm * 128;
  const int o0    = bo * 128;

  f32x4 acc[4][4];
#pragma unroll
  for (int i = 0; i < 4; i++)
#pragma unroll
    for (int j = 0; j < 4; j++) acc[i][j] = f32x4{0.f, 0.f, 0.f, 0.f};

  // staging: lane l writes LDS row (sub)=l>>3, chunk l&7. For swizzled layout,
  // logical chunk at that slot must be (l&7) ^ (l>>3)  -> pre-swizzle source.
  const int srow   = wv * 32 + (lane >> 3);                 // staging row (per lane)
  const int schunk = (((lane & 7) ^ (lane >> 3)) * 8);      // swizzled source col

  for (int kt = 0; kt < 8; ++kt) {
    const int k0 = kt * 64;
#pragma unroll
    for (int i = 0; i < 4; i++) {
      const ushort_t* g = A + (m0 + srow + i * 8) * 512 + k0 + schunk;
      gload_lds16(g, &As[wv * 32 + i * 8][0]);
    }
#pragma unroll
    for (int i = 0; i < 4; i++) {
      const ushort_t* g = W + (size_t)(o0 + srow + i * 8) * 512 + k0 + schunk;
      gload_lds16(g, &Ws[wv * 32 + i * 8][0]);
    }
    __syncthreads();
    const int fr = lane & 15;
#pragma unroll
    for (int kk = 0; kk < 2; ++kk) {
      // logical chunk ch, fragment rows have (row&7) == (lane&7)
      const int ch = kk * 4 + (lane >> 4);
      const int cb = ((ch ^ (lane & 7)) << 3);   // swizzled elem offset
      uint4 ar[4], br[4];
#pragma unroll
      for (int mi = 0; mi < 4; mi++)
        ar[mi] = *reinterpret_cast<const uint4*>(&As[wr * 64 + mi * 16 + fr][cb]);
#pragma unroll
      for (int ni = 0; ni < 4; ni++)
        br[ni] = *reinterpret_cast<const uint4*>(&Ws[wc * 64 + ni * 16 + fr][cb]);
#pragma unroll
      for (int mi = 0; mi < 4; mi++)
#pragma unroll
        for (int ni = 0; ni < 4; ni++)
          acc[mi][ni] = __builtin_amdgcn_mfma_f32_16x16x32_bf16(
              __builtin_bit_cast(bf16x8, ar[mi]),
              __builtin_bit_cast(bf16x8, br[ni]), acc[mi][ni], 0, 0, 0);
    }
    __syncthreads();
  }

  const int colbase = lane & 15;
  const int rowgrp  = (lane >> 4) * 4;

  if constexpr (EPI == 1) {
#pragma unroll
    for (int ni = 0; ni < 4; ni++) {
      const int o = o0 + wc * 64 + ni * 16 + colbase;
      const float bv = bias[o];
#pragma unroll
      for (int mi = 0; mi < 4; mi++) {
        const size_t mrow = m0 + wr * 64 + mi * 16 + rowgrp;
#pragma unroll
        for (int r = 0; r < 4; r++)
          out_f[(mrow + r) * 512 + o] = acc[mi][ni][r] + bv;
      }
    }
  } else {
#pragma unroll
    for (int mi = 0; mi < 4; mi++) {
#pragma unroll
      for (int r = 0; r < 4; r++) {
        const int t = (int)m0 + wr * 64 + mi * 16 + rowgrp + r;  // token
        const int b = t / 49;
        const int n = t - b * 49;
#pragma unroll
        for (int ni = 0; ni < 4; ni++) {
          const int o = o0 + wc * 64 + ni * 16 + colbase;
          const int which = o >> 9;
          const int h = (o >> 5) & 15;
          const int dd = o & 31;
          const size_t dst = (size_t)which * QKV_REG +
                             (((size_t)b * 16 + h) * 49 + n) * 32 + dd;
          out_qkv[dst] = f2bf(acc[mi][ni][r] + bias[o]);
        }
      }
    }
  }
}

// ---------------------------------------------------------------------------
// Attention: one block per (b,h). 4 waves, wave mt owns query rows
// [16*mt, 16*mt+16). S = scale*Q K^T + mask ; softmax ; O = P V / rowsum.
// Vt and Ps use the same chunk-XOR-swizzled LDS layout as the GEMM tiles.
// ---------------------------------------------------------------------------
__global__ __launch_bounds__(256) void k_attn(const ushort_t* __restrict__ qkv,
                                              const float* __restrict__ mask,
                                              ushort_t* __restrict__ aout) {
  __shared__ __align__(16) ushort_t Vt[32][64];      // V transposed: Vt[d][n] (swizzled)
  __shared__ __align__(16) ushort_t Ps[4][16][64];   // per-wave P tile (swizzled)

  const int tid  = threadIdx.x;
  const int lane = tid & 63;
  const int mt   = tid >> 6;              // wave id = query m-tile
  const int bh   = blockIdx.x;
  const int b    = bh >> 4, h = bh & 15;
  const int w    = b & 63;                // window index
  const size_t base = (size_t)bh * (49 * 32);
  const ushort_t* qb = qkv + base;
  const ushort_t* kb = qkv + QKV_REG + base;
  const ushort_t* vb = qkv + 2 * QKV_REG + base;

  // zero Vt (covers padded keys 49..63), then load V transposed (swizzled write)
  reinterpret_cast<uint4*>(&Vt[0][0])[tid] = make_uint4(0, 0, 0, 0);
  __syncthreads();
  if (tid < 196) {
    const int n = tid >> 2, d0 = (tid & 3) * 8;
    uint4 raw = *reinterpret_cast<const uint4*>(vb + n * 32 + d0);
    us8 e = __builtin_bit_cast(us8, raw);
#pragma unroll
    for (int j = 0; j < 8; j++) {
      // row = d0+j, (row&7) == j ; slot chunk = (n>>3) ^ j
      Vt[d0 + j][(((n >> 3) ^ j) << 3) | (n & 7)] = e[j];
    }
  }
  __syncthreads();

  const int arow = lane & 15;
  const int kc   = (lane >> 4) * 8;

  // S = Q K^T (one K=32 MFMA per 16x16 tile). Q/K fragments direct from global.
  uint4 qraw = *reinterpret_cast<const uint4*>(qb + (mt * 16 + arow) * 32 + kc);
  bf16x8 qa = __builtin_bit_cast(bf16x8, qraw);
  f32x4 s[4];
#pragma unroll
  for (int ni = 0; ni < 4; ni++) {
    uint4 kraw = *reinterpret_cast<const uint4*>(kb + (ni * 16 + arow) * 32 + kc);
    f32x4 z = {0.f, 0.f, 0.f, 0.f};
    s[ni] = __builtin_amdgcn_mfma_f32_16x16x32_bf16(
        qa, __builtin_bit_cast(bf16x8, kraw), z, 0, 0, 0);
  }

  // softmax: row r of D lives in 16-lane group, col = lane&15 (+16*ni)
  const int rg = (lane >> 4) * 4;
  float rsum[4];
#pragma unroll
  for (int r = 0; r < 4; r++) {
    const int qr = mt * 16 + rg + r;
    float sv[4];
    float mx = -1e30f;
#pragma unroll
    for (int ni = 0; ni < 4; ni++) {
      const int col = ni * 16 + arow;
      float v;
      if (qr < 49 && col < 49)
        v = s[ni][r] * SCALE_F + mask[(size_t)w * 2401 + qr * 49 + col];
      else
        v = -1e30f;
      sv[ni] = v;
      mx = fmaxf(mx, v);
    }
#pragma unroll
    for (int off = 1; off < 16; off <<= 1) mx = fmaxf(mx, __shfl_xor(mx, off));
    float sum = 0.f;
    const int prow = rg + r;
#pragma unroll
    for (int ni = 0; ni < 4; ni++) {
      float p = __expf(sv[ni] - mx);
      sum += p;
      const int pcol = ni * 16 + arow;
      Ps[mt][prow][(((pcol >> 3) ^ (prow & 7)) << 3) | (pcol & 7)] = f2bf(p);
    }
#pragma unroll
    for (int off = 1; off < 16; off <<= 1) sum += __shfl_xor(sum, off);
    rsum[r] = sum;
  }

  __syncthreads();  // order Ps ushort writes vs uint4 reads (cross-type aliasing)

  // O = P V : P rows from Ps (A-frag), V columns from Vt (B-frag).
  // Fragment rows have (row&7) == (lane&7) -> swizzled chunk = ch ^ (lane&7).
  f32x4 o0 = {0.f, 0.f, 0.f, 0.f}, o1 = {0.f, 0.f, 0.f, 0.f};
#pragma unroll
  for (int kk = 0; kk < 2; kk++) {
    const int ch = kk * 4 + (lane >> 4);
    const int cb = ((ch ^ (lane & 7)) << 3);
    uint4 praw = *reinterpret_cast<const uint4*>(&Ps[mt][arow][cb]);
    bf16x8 pa = __builtin_bit_cast(bf16x8, praw);
    uint4 v0 = *reinterpret_cast<const uint4*>(&Vt[arow][cb]);
    uint4 v1 = *reinterpret_cast<const uint4*>(&Vt[16 + arow][cb]);
    o0 = __builtin_amdgcn_mfma_f32_16x16x32_bf16(pa, __builtin_bit_cast(bf16x8, v0), o0, 0, 0, 0);
    o1 = __builtin_amdgcn_mfma_f32_16x16x32_bf16(pa, __builtin_bit_cast(bf16x8, v1), o1, 0, 0, 0);
  }

  // store: aout[(b*49+qr)*512 + h*32 + d] bf16
#pragma unroll
  for (int r = 0; r < 4; r++) {
    const int qr = mt * 16 + rg + r;
    if (qr < 49) {
      const float inv = 1.f / rsum[r];
      aout[((size_t)b * 49 + qr) * 512 + h * 32 + arow]      = f2bf(o0[r] * inv);
      aout[((size_t)b * 49 + qr) * 512 + h * 32 + 16 + arow] = f2bf(o1[r] * inv);
    }
  }
}

// ---------------------------------------------------------------------------
// launch
// ---------------------------------------------------------------------------
extern "C" void kernel_launch(void* const* d_in, const int* in_sizes, int n_in,
                              void* d_out, int out_size, void* d_ws, size_t ws_size,
                              hipStream_t stream) {
  const float* x      = (const float*)d_in[0];
  const float* mask   = (const float*)d_in[1];
  const float* W_qkv  = (const float*)d_in[2];
  const float* b_qkv  = (const float*)d_in[3];
  const float* W_proj = (const float*)d_in[4];
  const float* b_proj = (const float*)d_in[5];
  float* out = (float*)d_out;

  // ws layout (bf16 elems): xb | qkv(q,k,v) | attn_out | Wqkv_b | Wproj_b
  ushort_t* ws     = (ushort_t*)d_ws;
  ushort_t* xb     = ws;                                  // 51,380,224
  ushort_t* qkvb   = ws + 51380224UL;                     // 3*51,380,224
  ushort_t* aoutb  = ws + 205520896UL;                    // 51,380,224
  ushort_t* wqkvb  = ws + 256901120UL;                    // 786,432
  ushort_t* wprojb = ws + 257687552UL;                    // 262,144

  const int n4x = 51380224 / 4, n4q = 786432 / 4, n4p = 262144 / 4;
  k_cvt<<<(n4x + 255) / 256, 256, 0, stream>>>(x, xb, n4x);
  k_cvt<<<(n4q + 255) / 256, 256, 0, stream>>>(W_qkv, wqkvb, n4q);
  k_cvt<<<(n4p + 255) / 256, 256, 0, stream>>>(W_proj, wprojb, n4p);

  // GEMM1: [100352,512] x [1536,512]^T -> qkv scatter. 784 x 12 tiles (9408 % 8 == 0).
  k_gemm<0><<<784 * 12, 256, 0, stream>>>(xb, wqkvb, b_qkv, qkvb, nullptr, 12);

  // attention: one block per (b,h)
  k_attn<<<2048 * 16, 256, 0, stream>>>(qkvb, mask, aoutb);

  // GEMM2: [100352,512] x [512,512]^T + bias -> fp32 out. 784 x 4 tiles (3136 % 8 == 0).
  k_gemm<1><<<784 * 4, 256, 0, stream>>>(aoutb, wprojb, b_proj, nullptr, out, 4);
}